// Round 14
// baseline (361.569 us; speedup 1.0000x reference)
//
#include <hip/hip_runtime.h>
#include <hip/hip_fp16.h>
#include <hip/hip_cooperative_groups.h>

namespace cg = cooperative_groups;

// BusStopGNN round 14: entire CSR build (hist/cscan/btot/part/bsort) merged
// into ONE cooperative kernel with grid.sync() between phases -- deletes 4
// launch gaps + kernel-boundary drains. Phase bodies identical to round 13.
// mmf (layer-1 MFMA matmul), gatherW2 (fused gather+W2), gatherg (head)
// unchanged. 4 kernels total.

#define GNN_N 100000
#define GNN_E 1600000
#define NBUCK 391       // ceil(N/256), bucket = dst >> 8
#define CBLK  500       // cooperative grid blocks
#define EPB   3200      // E / CBLK, %4 == 0
#define SCTILE 16
#define STAGE_CAP 4864
#define DUMMY_OFF (GNN_N * 128)   // byte offset of zero row in fp16 tables

typedef _Float16 half8 __attribute__((ext_vector_type(8)));
typedef float f32x4 __attribute__((ext_vector_type(4)));

union CsrLds {
    int h[NBUCK];                          // P1 hist
    int tile[256][SCTILE + 1];             // P2 cscan (17.4 KB)
    int s[512];                            // P3 btot
    int off[NBUCK];                        // P4 part
    struct {
        int cnt[256];
        int pstart[256];
        int bump[256];
        int wtot[4];
        unsigned int stage[STAGE_CAP];     // P5 bsort (22.5 KB total)
    } p5;
};

// ---- cooperative CSR build: 5 phases, grid.sync between ----
__global__ __launch_bounds__(256) void k_csr(const int* __restrict__ src,
                                             const int* __restrict__ dst,
                                             int* __restrict__ hist,
                                             int* __restrict__ bbase,
                                             int* __restrict__ cbase,
                                             int* __restrict__ tot,
                                             unsigned int* __restrict__ part,
                                             int* __restrict__ csr,
                                             int* __restrict__ rowptr,
                                             int* __restrict__ deg,
                                             float* __restrict__ dis,
                                             __half* __restrict__ TA,
                                             __half* __restrict__ TB) {
    cg::grid_group grid = cg::this_grid();
    __shared__ CsrLds u;
    int bid = blockIdx.x;
    int t = threadIdx.x;

    // ---- P1: per-block LDS histogram (int4 sweep) + zero-row init ----
    for (int i = t; i < NBUCK; i += 256) u.h[i] = 0;
    if (bid == 0 && t < 16) {
        uint4 z = {0, 0, 0, 0};
        __half* base = (t < 8) ? TA : TB;
        *(uint4*)((char*)base + DUMMY_OFF + (t & 7) * 16) = z;
    }
    __syncthreads();
    {
        int e0 = bid * EPB, e1 = min(e0 + EPB, GNN_E);
        for (int e = e0 + t * 4; e < e1; e += 1024) {
            int4 d = *(const int4*)(dst + e);
            atomicAdd(&u.h[d.x >> 8], 1);
            atomicAdd(&u.h[d.y >> 8], 1);
            atomicAdd(&u.h[d.z >> 8], 1);
            atomicAdd(&u.h[d.w >> 8], 1);
        }
        __syncthreads();
        for (int i = t; i < NBUCK; i += 256)
            hist[bid * NBUCK + i] = u.h[i];
    }
    grid.sync();

    // ---- P2: tiled column scan over CBLK rows (blocks 0..24) ----
    if (bid < (NBUCK + SCTILE - 1) / SCTILE) {
        int k0 = bid * SCTILE;
        int lane = t & 63, w = t >> 6;
        int cSub = lane >> 4;
        int l16 = lane & 15;
        int col = w * 4 + cSub;
        int run = 0;
        for (int pass = 0; pass < 2; ++pass) {
            int r = pass * 256 + t;
#pragma unroll
            for (int i = 0; i < SCTILE; ++i) {
                int k = k0 + i;
                u.tile[t][i] = (k < NBUCK && r < CBLK) ? hist[r * NBUCK + k] : 0;
            }
            __syncthreads();
            for (int chunk = 0; chunk < 16; ++chunk) {
                int idx = chunk * 16 + l16;
                int v = u.tile[idx][col];
                int s = v;
#pragma unroll
                for (int o = 1; o < 16; o <<= 1) {
                    int tt = __shfl_up(s, o);
                    if (l16 >= o) s += tt;
                }
                u.tile[idx][col] = s - v + run;
                run += __shfl(s, lane | 15);
            }
            __syncthreads();
#pragma unroll
            for (int i = 0; i < SCTILE; ++i) {
                int k = k0 + i;
                if (k < NBUCK && r < CBLK) hist[r * NBUCK + k] = u.tile[t][i];
            }
            __syncthreads();
        }
        if (l16 == 0 && k0 + col < NBUCK) tot[k0 + col] = run;
    }
    grid.sync();

    // ---- P3: scan bucket totals -> bbase, cbase (block 0; 2 elems/thread) ----
    if (bid == 0) {
        int own0 = (t < NBUCK) ? tot[t] : 0;
        int own1 = (t + 256 < NBUCK) ? tot[t + 256] : 0;
        u.s[t] = own0;
        u.s[t + 256] = own1;
        __syncthreads();
        for (int off = 1; off < 512; off <<= 1) {
            int a = (t >= off) ? u.s[t - off] : 0;
            int b = (t + 256 >= off) ? u.s[t + 256 - off] : 0;
            __syncthreads();
            u.s[t] += a;
            u.s[t + 256] += b;
            __syncthreads();
        }
        if (t < NBUCK) {
            int ex = u.s[t] - own0;
            bbase[t] = ex;
            cbase[t] = (ex & ~3) + t * 772;
        }
        if (t + 256 < NBUCK) {
            int ex = u.s[t + 256] - own1;
            bbase[t + 256] = ex;
            cbase[t + 256] = (ex & ~3) + (t + 256) * 772;
        }
        if (t == 0) bbase[NBUCK] = GNN_E;
    }
    grid.sync();

    // ---- P4: partition edges (int4); pack (dst&255)<<17 | src ----
    for (int i = t; i < NBUCK; i += 256)
        u.off[i] = bbase[i] + hist[bid * NBUCK + i];
    __syncthreads();
    {
        int e0 = bid * EPB, e1 = min(e0 + EPB, GNN_E);
        for (int e = e0 + t * 4; e < e1; e += 1024) {
            int4 d = *(const int4*)(dst + e);
            int4 s = *(const int4*)(src + e);
            int sl0 = atomicAdd(&u.off[d.x >> 8], 1);
            part[sl0] = ((unsigned int)(d.x & 255) << 17) | (unsigned int)s.x;
            int sl1 = atomicAdd(&u.off[d.y >> 8], 1);
            part[sl1] = ((unsigned int)(d.y & 255) << 17) | (unsigned int)s.y;
            int sl2 = atomicAdd(&u.off[d.z >> 8], 1);
            part[sl2] = ((unsigned int)(d.z & 255) << 17) | (unsigned int)s.z;
            int sl3 = atomicAdd(&u.off[d.w >> 8], 1);
            part[sl3] = ((unsigned int)(d.w & 255) << 17) | (unsigned int)s.w;
        }
    }
    grid.sync();

    // ---- P5: per-bucket sort, LDS-staged, 4-padded runs (blocks 0..390) ----
    if (bid < NBUCK) {
        int k = bid;
        u.p5.cnt[t] = 0;
        __syncthreads();
        int e0 = bbase[k], e1 = bbase[k + 1];
        int m = e1 - e0;
        bool fits = (m <= STAGE_CAP);
        for (int i = t; i < m; i += 256) {
            unsigned int p = part[e0 + i];
            if (fits) u.p5.stage[i] = p;
            atomicAdd(&u.p5.cnt[p >> 17], 1);
        }
        __syncthreads();
        int c = u.p5.cnt[t];
        int padded = (c + 3) & ~3;
        int v = padded;
#pragma unroll
        for (int o = 1; o < 64; o <<= 1) {
            int uu = __shfl_up(v, o);
            if ((t & 63) >= o) v += uu;
        }
        if ((t & 63) == 63) u.p5.wtot[t >> 6] = v;
        __syncthreads();
        int wb = 0;
#pragma unroll
        for (int j = 0; j < 4; ++j)
            if (j < (t >> 6)) wb += u.p5.wtot[j];
        int ps = wb + v - padded;
        u.p5.pstart[t] = ps;
        u.p5.bump[t] = ps;
        __syncthreads();
        int cb = cbase[k];
        int node = k * 256 + t;
        if (node < GNN_N) {
            rowptr[node] = cb + ps;
            deg[node]    = padded;
            dis[node]    = rsqrtf((float)c + 1.0f);
        }
        for (int i = t; i < m; i += 256) {
            unsigned int p = fits ? u.p5.stage[i] : part[e0 + i];
            int slot = atomicAdd(&u.p5.bump[p >> 17], 1);
            csr[cb + slot] = (int)(p & 0x1FFFF) << 7;
        }
        __syncthreads();
        if (node < GNN_N) {
            for (int i = c; i < padded; ++i)
                csr[cb + ps + i] = DUMMY_OFF;
        }
    }
}

// ---- MFMA 64x64 matmul (layer 1): TA[row] = fp16((x@W1)[row]*dis[row]) ----
__global__ __launch_bounds__(256) void k_mmf(const float* __restrict__ X,
                                             const float* __restrict__ W,
                                             const float* __restrict__ dis,
                                             __half* __restrict__ Y, int n) {
    __shared__ __align__(16) __half Xs[64][72];
    __shared__ __align__(16) __half Wt[64][72];
    __shared__ float disS[64];
    int tid = threadIdx.x;
    int base = blockIdx.x * 64;
    for (int i = tid; i < 4096; i += 256) {
        int k = i >> 6, j = i & 63;
        Wt[j][k] = __float2half(W[i]);
    }
    if (tid < 64) disS[tid] = (base + tid < n) ? dis[base + tid] : 0.f;
#pragma unroll
    for (int ii = 0; ii < 4; ++ii) {
        int i = ii * 256 + tid;
        int r = i >> 4, c4 = i & 15;
        int row = base + r;
        float4 vv = (row < n) ? ((const float4*)(X + (size_t)row * 64))[c4]
                              : make_float4(0.f, 0.f, 0.f, 0.f);
        *(__half2*)&Xs[r][c4 * 4 + 0] = __floats2half2_rn(vv.x, vv.y);
        *(__half2*)&Xs[r][c4 * 4 + 2] = __floats2half2_rn(vv.z, vv.w);
    }
    __syncthreads();
    int w = tid >> 6, lane = tid & 63;
    int ar = w * 16 + (lane & 15);
    int ak = (lane >> 4) * 8;
    half8 a0 = *(const half8*)&Xs[ar][ak];
    half8 a1 = *(const half8*)&Xs[ar][32 + ak];
    f32x4 acc0 = {0.f, 0.f, 0.f, 0.f}, acc1 = acc0, acc2 = acc0, acc3 = acc0;
#define MMCOL(ACC, C) {                                                   \
        half8 b0 = *(const half8*)&Wt[(C) * 16 + (lane & 15)][ak];        \
        half8 b1 = *(const half8*)&Wt[(C) * 16 + (lane & 15)][32 + ak];   \
        ACC = __builtin_amdgcn_mfma_f32_16x16x32_f16(a0, b0, ACC, 0, 0, 0); \
        ACC = __builtin_amdgcn_mfma_f32_16x16x32_f16(a1, b1, ACC, 0, 0, 0); }
    MMCOL(acc0, 0) MMCOL(acc1, 1) MMCOL(acc2, 2) MMCOL(acc3, 3)
#undef MMCOL
    __syncthreads();
#define DST(ACC, C) {                                                     \
        _Pragma("unroll")                                                 \
        for (int i = 0; i < 4; ++i) {                                     \
            int rl = w * 16 + (lane >> 4) * 4 + i;                        \
            Xs[rl][(C) * 16 + (lane & 15)] = __float2half(ACC[i] * disS[rl]); \
        } }
    DST(acc0, 0) DST(acc1, 1) DST(acc2, 2) DST(acc3, 3)
#undef DST
    __syncthreads();
#pragma unroll
    for (int ii = 0; ii < 2; ++ii) {
        int i = ii * 256 + tid;
        int r = i >> 3, c8 = i & 7;
        int row = base + r;
        if (row < n)
            *(uint4*)(Y + (size_t)row * 64 + c8 * 8) = *(const uint4*)&Xs[r][c8 * 8];
    }
}

#define ACC8(A, U) {                                                     \
    float2 f_;                                                           \
    f_ = __half22float2(*(__half2*)&U.x); A[0] += f_.x; A[1] += f_.y;    \
    f_ = __half22float2(*(__half2*)&U.y); A[2] += f_.x; A[3] += f_.y;    \
    f_ = __half22float2(*(__half2*)&U.z); A[4] += f_.x; A[5] += f_.y;    \
    f_ = __half22float2(*(__half2*)&U.w); A[6] += f_.x; A[7] += f_.y; }

// ---- fused gather + W2 matmul: TB[i] = fp16( (relu(z_i)@W2) * dis[i] ) ----
__global__ __launch_bounds__(256) void k_gatherW2(
        const __half* __restrict__ T, const int* __restrict__ csr,
        const int* __restrict__ rowptr, const int* __restrict__ deg,
        const float* __restrict__ dis, const float* __restrict__ bias,
        const float* __restrict__ W2, __half* __restrict__ TB) {
    __shared__ __align__(16) __half Wt[64][72];   // W2^T fp16
    __shared__ __align__(16) __half Rt[32][72];   // h1 tile, then D tile
    __shared__ float disT[32];
    int tid = threadIdx.x;
    for (int i = tid; i < 4096; i += 256) {
        int k = i >> 6, j = i & 63;
        Wt[j][k] = __float2half(W2[i]);
    }
    int q = tid & 7;
    int nl = tid >> 3;
    int node = blockIdx.x * 32 + nl;       // exact grid, always < N
    int base = rowptr[node];
    int cnt  = deg[node];
    float dd = dis[node];
    if (q == 0) disT[nl] = dd;
    const char* Tq = (const char*)T + q * 16;
    float a0[8], a1[8];
#pragma unroll
    for (int i = 0; i < 8; ++i) { a0[i] = 0.f; a1[i] = 0.f; }
    int j = 0;
    for (; j + 8 <= cnt; j += 8) {
        int4 c0 = *(const int4*)(csr + base + j);
        int4 c1 = *(const int4*)(csr + base + j + 4);
        uint4 u0 = *(const uint4*)(Tq + (size_t)(unsigned)c0.x);
        uint4 u1 = *(const uint4*)(Tq + (size_t)(unsigned)c0.y);
        uint4 u2 = *(const uint4*)(Tq + (size_t)(unsigned)c0.z);
        uint4 u3 = *(const uint4*)(Tq + (size_t)(unsigned)c0.w);
        uint4 u4 = *(const uint4*)(Tq + (size_t)(unsigned)c1.x);
        uint4 u5 = *(const uint4*)(Tq + (size_t)(unsigned)c1.y);
        uint4 u6 = *(const uint4*)(Tq + (size_t)(unsigned)c1.z);
        uint4 u7 = *(const uint4*)(Tq + (size_t)(unsigned)c1.w);
        ACC8(a0, u0) ACC8(a1, u1) ACC8(a0, u2) ACC8(a1, u3)
        ACC8(a0, u4) ACC8(a1, u5) ACC8(a0, u6) ACC8(a1, u7)
    }
    if (j < cnt) {
        int4 c0 = *(const int4*)(csr + base + j);
        uint4 u0 = *(const uint4*)(Tq + (size_t)(unsigned)c0.x);
        uint4 u1 = *(const uint4*)(Tq + (size_t)(unsigned)c0.y);
        uint4 u2 = *(const uint4*)(Tq + (size_t)(unsigned)c0.z);
        uint4 u3 = *(const uint4*)(Tq + (size_t)(unsigned)c0.w);
        ACC8(a0, u0) ACC8(a1, u1) ACC8(a0, u2) ACC8(a1, u3)
    }
    uint4 us = *(const uint4*)(Tq + (size_t)node * 128);   // self row
    ACC8(a1, us)
    float4 bb0 = ((const float4*)bias)[q * 2 + 0];
    float4 bb1 = ((const float4*)bias)[q * 2 + 1];
    float r[8];
    r[0] = fmaxf(dd * (a0[0] + a1[0]) + bb0.x, 0.f);
    r[1] = fmaxf(dd * (a0[1] + a1[1]) + bb0.y, 0.f);
    r[2] = fmaxf(dd * (a0[2] + a1[2]) + bb0.z, 0.f);
    r[3] = fmaxf(dd * (a0[3] + a1[3]) + bb0.w, 0.f);
    r[4] = fmaxf(dd * (a0[4] + a1[4]) + bb1.x, 0.f);
    r[5] = fmaxf(dd * (a0[5] + a1[5]) + bb1.y, 0.f);
    r[6] = fmaxf(dd * (a0[6] + a1[6]) + bb1.z, 0.f);
    r[7] = fmaxf(dd * (a0[7] + a1[7]) + bb1.w, 0.f);
    uint4 u;
    *(__half2*)&u.x = __floats2half2_rn(r[0], r[1]);
    *(__half2*)&u.y = __floats2half2_rn(r[2], r[3]);
    *(__half2*)&u.z = __floats2half2_rn(r[4], r[5]);
    *(__half2*)&u.w = __floats2half2_rn(r[6], r[7]);
    *(uint4*)&Rt[nl][q * 8] = u;
    __syncthreads();
    int w = tid >> 6, lane = tid & 63;
    int band = w >> 1, cg2 = w & 1;
    int ar = band * 16 + (lane & 15);
    int ak = (lane >> 4) * 8;
    half8 fa0 = *(const half8*)&Rt[ar][ak];
    half8 fa1 = *(const half8*)&Rt[ar][32 + ak];
    f32x4 acc0 = {0.f, 0.f, 0.f, 0.f}, acc1 = acc0;
    {
        int c0 = cg2 * 2, c1 = cg2 * 2 + 1;
        half8 b00 = *(const half8*)&Wt[c0 * 16 + (lane & 15)][ak];
        half8 b01 = *(const half8*)&Wt[c0 * 16 + (lane & 15)][32 + ak];
        half8 b10 = *(const half8*)&Wt[c1 * 16 + (lane & 15)][ak];
        half8 b11 = *(const half8*)&Wt[c1 * 16 + (lane & 15)][32 + ak];
        acc0 = __builtin_amdgcn_mfma_f32_16x16x32_f16(fa0, b00, acc0, 0, 0, 0);
        acc0 = __builtin_amdgcn_mfma_f32_16x16x32_f16(fa1, b01, acc0, 0, 0, 0);
        acc1 = __builtin_amdgcn_mfma_f32_16x16x32_f16(fa0, b10, acc1, 0, 0, 0);
        acc1 = __builtin_amdgcn_mfma_f32_16x16x32_f16(fa1, b11, acc1, 0, 0, 0);
    }
    __syncthreads();
#pragma unroll
    for (int i = 0; i < 4; ++i) {
        int rl = band * 16 + (lane >> 4) * 4 + i;
        float dsc = disT[rl];
        Rt[rl][(cg2 * 2 + 0) * 16 + (lane & 15)] = __float2half(acc0[i] * dsc);
        Rt[rl][(cg2 * 2 + 1) * 16 + (lane & 15)] = __float2half(acc1[i] * dsc);
    }
    __syncthreads();
    {
        int r8 = tid >> 3, c8 = tid & 7;
        int row = blockIdx.x * 32 + r8;
        *(uint4*)(TB + (size_t)row * 64 + c8 * 8) = *(const uint4*)&Rt[r8][c8 * 8];
    }
}

// ---- head gather: out[i] = dot(relu(dis*(sum TB rows)+b2), Wp) + bp ----
__global__ __launch_bounds__(256) void k_gatherg(
        const __half* __restrict__ T, const int* __restrict__ csr,
        const int* __restrict__ rowptr, const int* __restrict__ deg,
        const float* __restrict__ dis, const float* __restrict__ bias,
        const float* __restrict__ Wp, const float* __restrict__ bp,
        float* __restrict__ out, int n) {
    int tid = threadIdx.x;
    int q = tid & 7;
    int node = blockIdx.x * 32 + (tid >> 3);
    if (node >= n) return;
    int base = rowptr[node];
    int cnt  = deg[node];
    float dd = dis[node];
    const char* Tq = (const char*)T + q * 16;
    float a0[8], a1[8];
#pragma unroll
    for (int i = 0; i < 8; ++i) { a0[i] = 0.f; a1[i] = 0.f; }
    int j = 0;
    for (; j + 8 <= cnt; j += 8) {
        int4 c0 = *(const int4*)(csr + base + j);
        int4 c1 = *(const int4*)(csr + base + j + 4);
        uint4 u0 = *(const uint4*)(Tq + (size_t)(unsigned)c0.x);
        uint4 u1 = *(const uint4*)(Tq + (size_t)(unsigned)c0.y);
        uint4 u2 = *(const uint4*)(Tq + (size_t)(unsigned)c0.z);
        uint4 u3 = *(const uint4*)(Tq + (size_t)(unsigned)c0.w);
        uint4 u4 = *(const uint4*)(Tq + (size_t)(unsigned)c1.x);
        uint4 u5 = *(const uint4*)(Tq + (size_t)(unsigned)c1.y);
        uint4 u6 = *(const uint4*)(Tq + (size_t)(unsigned)c1.z);
        uint4 u7 = *(const uint4*)(Tq + (size_t)(unsigned)c1.w);
        ACC8(a0, u0) ACC8(a1, u1) ACC8(a0, u2) ACC8(a1, u3)
        ACC8(a0, u4) ACC8(a1, u5) ACC8(a0, u6) ACC8(a1, u7)
    }
    if (j < cnt) {
        int4 c0 = *(const int4*)(csr + base + j);
        uint4 u0 = *(const uint4*)(Tq + (size_t)(unsigned)c0.x);
        uint4 u1 = *(const uint4*)(Tq + (size_t)(unsigned)c0.y);
        uint4 u2 = *(const uint4*)(Tq + (size_t)(unsigned)c0.z);
        uint4 u3 = *(const uint4*)(Tq + (size_t)(unsigned)c0.w);
        ACC8(a0, u0) ACC8(a1, u1) ACC8(a0, u2) ACC8(a1, u3)
    }
    uint4 us = *(const uint4*)(Tq + (size_t)node * 128);
    ACC8(a1, us)
    float4 bb0 = ((const float4*)bias)[q * 2 + 0];
    float4 bb1 = ((const float4*)bias)[q * 2 + 1];
    float r[8];
    r[0] = fmaxf(dd * (a0[0] + a1[0]) + bb0.x, 0.f);
    r[1] = fmaxf(dd * (a0[1] + a1[1]) + bb0.y, 0.f);
    r[2] = fmaxf(dd * (a0[2] + a1[2]) + bb0.z, 0.f);
    r[3] = fmaxf(dd * (a0[3] + a1[3]) + bb0.w, 0.f);
    r[4] = fmaxf(dd * (a0[4] + a1[4]) + bb1.x, 0.f);
    r[5] = fmaxf(dd * (a0[5] + a1[5]) + bb1.y, 0.f);
    r[6] = fmaxf(dd * (a0[6] + a1[6]) + bb1.z, 0.f);
    r[7] = fmaxf(dd * (a0[7] + a1[7]) + bb1.w, 0.f);
    float4 w0 = ((const float4*)Wp)[q * 2 + 0];
    float4 w1 = ((const float4*)Wp)[q * 2 + 1];
    float s = r[0] * w0.x + r[1] * w0.y + r[2] * w0.z + r[3] * w0.w
            + r[4] * w1.x + r[5] * w1.y + r[6] * w1.z + r[7] * w1.w;
#pragma unroll
    for (int m = 1; m <= 4; m <<= 1) s += __shfl_xor(s, m);
    if (q == 0) out[node] = s + bp[0];
}

extern "C" void kernel_launch(void* const* d_in, const int* in_sizes, int n_in,
                              void* d_out, int out_size, void* d_ws, size_t ws_size,
                              hipStream_t stream) {
    const float* x  = (const float*)d_in[0];
    const int*   ei = (const int*)d_in[1];
    const float* W1 = (const float*)d_in[2];
    const float* b1 = (const float*)d_in[3];
    const float* W2 = (const float*)d_in[4];
    const float* b2 = (const float*)d_in[5];
    const float* Wp = (const float*)d_in[6];
    const float* bp = (const float*)d_in[7];
    float* out = (float*)d_out;

    const int N = GNN_N, E = GNN_E;
    const int* srcv = ei;
    const int* dstv = ei + E;

    // workspace layout (bytes):
    //   hist   @ 0          : CBLK*NBUCK ints = 782,000
    //   bbase  @ 784,000    : 392 ints
    //   cbase  @ 785,600    : 392 ints
    //   rowptr @ 787,200    : N ints
    //   deg    @ 1,187,200  : N ints
    //   dis/tot@ 1,587,200  : N floats (tot aliases; dis written in P5)
    //   csr    @ 1,987,200  : ~1.91M ints padded (7.61 MB)
    //   TA     @ 9,597,440  : (N+1)*64 fp16 (12.8 MB)
    //   TB     @ 22,400,000 : (N+1)*64 fp16 (12.8 MB)
    //   part   @ 35,200,256 : E u32 (6.4 MB)    [total ~41.6 MB]
    char* ws = (char*)d_ws;
    int*    hist   = (int*)(ws + 0);
    int*    bbase  = (int*)(ws + 784000);
    int*    cbase  = (int*)(ws + 785600);
    int*    rowptr = (int*)(ws + 787200);
    int*    deg    = (int*)(ws + 1187200);
    float*  dis    = (float*)(ws + 1587200);
    int*    tot    = (int*)(ws + 1587200);
    int*    csr    = (int*)(ws + 1987200);
    __half* TA     = (__half*)(ws + 9597440);
    __half* TB     = (__half*)(ws + 22400000);
    unsigned int* part = (unsigned int*)(ws + 35200256);

    // cooperative CSR build (one kernel, 5 phases)
    {
        void* args[] = {(void*)&srcv, (void*)&dstv, (void*)&hist, (void*)&bbase,
                        (void*)&cbase, (void*)&tot, (void*)&part, (void*)&csr,
                        (void*)&rowptr, (void*)&deg, (void*)&dis, (void*)&TA,
                        (void*)&TB};
        hipLaunchCooperativeKernel((void*)k_csr, dim3(CBLK), dim3(256),
                                   args, 0, stream);
    }

    // layer 1 matmul: TA = fp16((x@W1)*dis)
    k_mmf<<<(N + 63) / 64, 256, 0, stream>>>(x, W1, dis, TA, N);
    // fused layer-1 gather + layer-2 matmul: TB = fp16((relu(gather)@W2)*dis)
    k_gatherW2<<<N / 32, 256, 0, stream>>>(TA, csr, rowptr, deg, dis, b1, W2, TB);
    // layer-2 gather + head
    k_gatherg<<<(N + 31) / 32, 256, 0, stream>>>(TB, csr, rowptr, deg, dis,
                                                 b2, Wp, bp, out, N);
}

// Round 15
// 127.073 us; speedup vs baseline: 2.8454x; 2.8454x over previous
//
#include <hip/hip_runtime.h>
#include <hip/hip_fp16.h>

// BusStopGNN round 15: REVERT of round-14's cooperative merge (294us: coop
// co-residency pinned occupancy at 23% for all phases + 500-block P4 broke
// line-exclusive partition writes -> false sharing). Back to the proven
// round-13 multi-kernel pipeline, minus k_btot: part/bsort compute bucket
// bases from tot via an in-LDS redundant scan (one fewer launch).

#define GNN_N 100000
#define GNN_E 1600000
#define NBUCK 391       // ceil(N/256), bucket = dst >> 8
#define HBLK  500       // hist blocks
#define EPBH  3200      // E / HBLK, %4 == 0
#define NBLK  250       // part blocks (line-exclusive write granularity)
#define EPB   6400      // E / NBLK, %4 == 0
#define SCTILE 16
#define STAGE_CAP 4864
#define DUMMY_OFF (GNN_N * 128)   // byte offset of zero row in fp16 tables

typedef _Float16 half8 __attribute__((ext_vector_type(8)));
typedef float f32x4 __attribute__((ext_vector_type(4)));

// ---- Pass 1: per-block LDS histogram (int4 sweep) + zero-row init ----
__global__ __launch_bounds__(256) void k_hist(const int* __restrict__ dst,
                                              int* __restrict__ hist,
                                              __half* __restrict__ TA,
                                              __half* __restrict__ TB) {
    __shared__ int h[NBUCK];
    for (int i = threadIdx.x; i < NBUCK; i += 256) h[i] = 0;
    if (blockIdx.x == 0 && threadIdx.x < 16) {     // zero row N of both tables
        uint4 z = {0, 0, 0, 0};
        int t = threadIdx.x;
        __half* base = (t < 8) ? TA : TB;
        *(uint4*)((char*)base + DUMMY_OFF + (t & 7) * 16) = z;
    }
    __syncthreads();
    int b = blockIdx.x;
    int e0 = b * EPBH, e1 = min(e0 + EPBH, GNN_E);
    for (int e = e0 + threadIdx.x * 4; e < e1; e += 1024) {
        int4 d = *(const int4*)(dst + e);
        atomicAdd(&h[d.x >> 8], 1);
        atomicAdd(&h[d.y >> 8], 1);
        atomicAdd(&h[d.z >> 8], 1);
        atomicAdd(&h[d.w >> 8], 1);
    }
    __syncthreads();
    for (int i = threadIdx.x; i < NBUCK; i += 256)
        hist[b * NBUCK + i] = h[i];
}

// ---- Pass 2: tiled column scan over HBLK rows (2 passes of 256) ----
__global__ __launch_bounds__(256) void k_cscan(int* __restrict__ hist,
                                               int* __restrict__ tot) {
    __shared__ int tile[256][SCTILE + 1];
    int k0 = blockIdx.x * SCTILE;
    int b = threadIdx.x;
    int lane = b & 63, w = b >> 6;
    int cSub = lane >> 4;
    int l16 = lane & 15;
    int col = w * 4 + cSub;
    int run = 0;
    for (int pass = 0; pass < 2; ++pass) {
        int r = pass * 256 + b;
#pragma unroll
        for (int i = 0; i < SCTILE; ++i) {
            int k = k0 + i;
            tile[b][i] = (k < NBUCK && r < HBLK) ? hist[r * NBUCK + k] : 0;
        }
        __syncthreads();
        for (int chunk = 0; chunk < 16; ++chunk) {
            int idx = chunk * 16 + l16;
            int v = tile[idx][col];
            int s = v;
#pragma unroll
            for (int o = 1; o < 16; o <<= 1) {
                int t = __shfl_up(s, o);
                if (l16 >= o) s += t;
            }
            tile[idx][col] = s - v + run;
            run += __shfl(s, lane | 15);
        }
        __syncthreads();
#pragma unroll
        for (int i = 0; i < SCTILE; ++i) {
            int k = k0 + i;
            if (k < NBUCK && r < HBLK) hist[r * NBUCK + k] = tile[b][i];
        }
        __syncthreads();
    }
    if (l16 == 0 && k0 + col < NBUCK) tot[k0 + col] = run;
}

// ---- Pass 3: partition edges (int4); bucket bases via in-LDS scan of tot ----
__global__ __launch_bounds__(256) void k_part(const int* __restrict__ src,
                                              const int* __restrict__ dst,
                                              const int* __restrict__ hist,
                                              const int* __restrict__ tot,
                                              unsigned int* __restrict__ part) {
    __shared__ int offA[NBUCK];
    __shared__ int sc[512];
    int b = blockIdx.x;
    int t = threadIdx.x;
    // redundant exclusive scan of tot (391 vals) -> bucket bases
    int own0 = (t < NBUCK) ? tot[t] : 0;
    int own1 = (t + 256 < NBUCK) ? tot[t + 256] : 0;
    sc[t] = own0;
    sc[t + 256] = own1;
    __syncthreads();
    for (int o = 1; o < 512; o <<= 1) {
        int a = (t >= o) ? sc[t - o] : 0;
        int c = sc[t + 256 - o];           // t+256 >= 256 >= o always
        __syncthreads();
        sc[t] += a;
        sc[t + 256] += c;
        __syncthreads();
    }
    if (t < NBUCK)
        offA[t] = (sc[t] - own0) + hist[(2 * b) * NBUCK + t];
    if (t + 256 < NBUCK)
        offA[t + 256] = (sc[t + 256] - own1) + hist[(2 * b) * NBUCK + t + 256];
    __syncthreads();
    int e0 = b * EPB, e1 = min(e0 + EPB, GNN_E);
    for (int e = e0 + t * 4; e < e1; e += 1024) {
        int4 d = *(const int4*)(dst + e);
        int4 s = *(const int4*)(src + e);
        int sl0 = atomicAdd(&offA[d.x >> 8], 1);
        part[sl0] = ((unsigned int)(d.x & 255) << 17) | (unsigned int)s.x;
        int sl1 = atomicAdd(&offA[d.y >> 8], 1);
        part[sl1] = ((unsigned int)(d.y & 255) << 17) | (unsigned int)s.y;
        int sl2 = atomicAdd(&offA[d.z >> 8], 1);
        part[sl2] = ((unsigned int)(d.z & 255) << 17) | (unsigned int)s.z;
        int sl3 = atomicAdd(&offA[d.w >> 8], 1);
        part[sl3] = ((unsigned int)(d.w & 255) << 17) | (unsigned int)s.w;
    }
}

// ---- Pass 4: per-bucket sort; bases via in-LDS scan; 4-padded runs ----
__global__ __launch_bounds__(256) void k_bsort(const unsigned int* __restrict__ part,
                                               const int* __restrict__ tot,
                                               int* __restrict__ csr,
                                               int* __restrict__ rowptr,
                                               int* __restrict__ deg,
                                               float* __restrict__ dis) {
    __shared__ int cnt[256];
    __shared__ int pstart[256];
    __shared__ int bump[256];
    __shared__ int wtot[4];
    __shared__ int sc[512];
    __shared__ unsigned int stage[STAGE_CAP];
    int k = blockIdx.x;
    int t = threadIdx.x;
    // redundant scan of tot -> this bucket's [e0,e1) and padded base cb
    int own0 = (t < NBUCK) ? tot[t] : 0;
    int own1 = (t + 256 < NBUCK) ? tot[t + 256] : 0;
    sc[t] = own0;
    sc[t + 256] = own1;
    cnt[t] = 0;
    __syncthreads();
    for (int o = 1; o < 512; o <<= 1) {
        int a = (t >= o) ? sc[t - o] : 0;
        int c = sc[t + 256 - o];
        __syncthreads();
        sc[t] += a;
        sc[t + 256] += c;
        __syncthreads();
    }
    int incl = sc[k];                      // inclusive prefix at bucket k
    int totk = tot[k];
    int e0 = incl - totk, e1 = incl;
    int cb = (e0 & ~3) + k * 772;
    int m = e1 - e0;
    bool fits = (m <= STAGE_CAP);
    for (int i = t; i < m; i += 256) {
        unsigned int p = part[e0 + i];
        if (fits) stage[i] = p;
        atomicAdd(&cnt[p >> 17], 1);
    }
    __syncthreads();
    int c = cnt[t];
    int padded = (c + 3) & ~3;
    int v = padded;
#pragma unroll
    for (int o = 1; o < 64; o <<= 1) {
        int u = __shfl_up(v, o);
        if ((t & 63) >= o) v += u;
    }
    if ((t & 63) == 63) wtot[t >> 6] = v;
    __syncthreads();
    int wb = 0;
#pragma unroll
    for (int j = 0; j < 4; ++j)
        if (j < (t >> 6)) wb += wtot[j];
    int ps = wb + v - padded;
    pstart[t] = ps;
    bump[t] = ps;
    __syncthreads();
    int node = k * 256 + t;
    if (node < GNN_N) {
        rowptr[node] = cb + ps;
        deg[node]    = padded;
        dis[node]    = rsqrtf((float)c + 1.0f);
    }
    for (int i = t; i < m; i += 256) {
        unsigned int p = fits ? stage[i] : part[e0 + i];
        int slot = atomicAdd(&bump[p >> 17], 1);
        csr[cb + slot] = (int)(p & 0x1FFFF) << 7;
    }
    __syncthreads();
    if (node < GNN_N) {
        for (int i = c; i < padded; ++i)
            csr[cb + ps + i] = DUMMY_OFF;
    }
}

// ---- MFMA 64x64 matmul (layer 1): TA[row] = fp16((x@W1)[row]*dis[row]) ----
__global__ __launch_bounds__(256) void k_mmf(const float* __restrict__ X,
                                             const float* __restrict__ W,
                                             const float* __restrict__ dis,
                                             __half* __restrict__ Y, int n) {
    __shared__ __align__(16) __half Xs[64][72];
    __shared__ __align__(16) __half Wt[64][72];
    __shared__ float disS[64];
    int tid = threadIdx.x;
    int base = blockIdx.x * 64;
    for (int i = tid; i < 4096; i += 256) {
        int k = i >> 6, j = i & 63;
        Wt[j][k] = __float2half(W[i]);
    }
    if (tid < 64) disS[tid] = (base + tid < n) ? dis[base + tid] : 0.f;
#pragma unroll
    for (int ii = 0; ii < 4; ++ii) {
        int i = ii * 256 + tid;
        int r = i >> 4, c4 = i & 15;
        int row = base + r;
        float4 vv = (row < n) ? ((const float4*)(X + (size_t)row * 64))[c4]
                              : make_float4(0.f, 0.f, 0.f, 0.f);
        *(__half2*)&Xs[r][c4 * 4 + 0] = __floats2half2_rn(vv.x, vv.y);
        *(__half2*)&Xs[r][c4 * 4 + 2] = __floats2half2_rn(vv.z, vv.w);
    }
    __syncthreads();
    int w = tid >> 6, lane = tid & 63;
    int ar = w * 16 + (lane & 15);
    int ak = (lane >> 4) * 8;
    half8 a0 = *(const half8*)&Xs[ar][ak];
    half8 a1 = *(const half8*)&Xs[ar][32 + ak];
    f32x4 acc0 = {0.f, 0.f, 0.f, 0.f}, acc1 = acc0, acc2 = acc0, acc3 = acc0;
#define MMCOL(ACC, C) {                                                   \
        half8 b0 = *(const half8*)&Wt[(C) * 16 + (lane & 15)][ak];        \
        half8 b1 = *(const half8*)&Wt[(C) * 16 + (lane & 15)][32 + ak];   \
        ACC = __builtin_amdgcn_mfma_f32_16x16x32_f16(a0, b0, ACC, 0, 0, 0); \
        ACC = __builtin_amdgcn_mfma_f32_16x16x32_f16(a1, b1, ACC, 0, 0, 0); }
    MMCOL(acc0, 0) MMCOL(acc1, 1) MMCOL(acc2, 2) MMCOL(acc3, 3)
#undef MMCOL
    __syncthreads();
#define DST(ACC, C) {                                                     \
        _Pragma("unroll")                                                 \
        for (int i = 0; i < 4; ++i) {                                     \
            int rl = w * 16 + (lane >> 4) * 4 + i;                        \
            Xs[rl][(C) * 16 + (lane & 15)] = __float2half(ACC[i] * disS[rl]); \
        } }
    DST(acc0, 0) DST(acc1, 1) DST(acc2, 2) DST(acc3, 3)
#undef DST
    __syncthreads();
#pragma unroll
    for (int ii = 0; ii < 2; ++ii) {
        int i = ii * 256 + tid;
        int r = i >> 3, c8 = i & 7;
        int row = base + r;
        if (row < n)
            *(uint4*)(Y + (size_t)row * 64 + c8 * 8) = *(const uint4*)&Xs[r][c8 * 8];
    }
}

#define ACC8(A, U) {                                                     \
    float2 f_;                                                           \
    f_ = __half22float2(*(__half2*)&U.x); A[0] += f_.x; A[1] += f_.y;    \
    f_ = __half22float2(*(__half2*)&U.y); A[2] += f_.x; A[3] += f_.y;    \
    f_ = __half22float2(*(__half2*)&U.z); A[4] += f_.x; A[5] += f_.y;    \
    f_ = __half22float2(*(__half2*)&U.w); A[6] += f_.x; A[7] += f_.y; }

// ---- fused gather + W2 matmul: TB[i] = fp16( (relu(z_i)@W2) * dis[i] ) ----
__global__ __launch_bounds__(256) void k_gatherW2(
        const __half* __restrict__ T, const int* __restrict__ csr,
        const int* __restrict__ rowptr, const int* __restrict__ deg,
        const float* __restrict__ dis, const float* __restrict__ bias,
        const float* __restrict__ W2, __half* __restrict__ TB) {
    __shared__ __align__(16) __half Wt[64][72];   // W2^T fp16
    __shared__ __align__(16) __half Rt[32][72];   // h1 tile, then D tile
    __shared__ float disT[32];
    int tid = threadIdx.x;
    for (int i = tid; i < 4096; i += 256) {
        int k = i >> 6, j = i & 63;
        Wt[j][k] = __float2half(W2[i]);
    }
    int q = tid & 7;
    int nl = tid >> 3;
    int node = blockIdx.x * 32 + nl;       // exact grid, always < N
    int base = rowptr[node];
    int cnt  = deg[node];
    float dd = dis[node];
    if (q == 0) disT[nl] = dd;
    const char* Tq = (const char*)T + q * 16;
    float a0[8], a1[8];
#pragma unroll
    for (int i = 0; i < 8; ++i) { a0[i] = 0.f; a1[i] = 0.f; }
    int j = 0;
    for (; j + 8 <= cnt; j += 8) {
        int4 c0 = *(const int4*)(csr + base + j);
        int4 c1 = *(const int4*)(csr + base + j + 4);
        uint4 u0 = *(const uint4*)(Tq + (size_t)(unsigned)c0.x);
        uint4 u1 = *(const uint4*)(Tq + (size_t)(unsigned)c0.y);
        uint4 u2 = *(const uint4*)(Tq + (size_t)(unsigned)c0.z);
        uint4 u3 = *(const uint4*)(Tq + (size_t)(unsigned)c0.w);
        uint4 u4 = *(const uint4*)(Tq + (size_t)(unsigned)c1.x);
        uint4 u5 = *(const uint4*)(Tq + (size_t)(unsigned)c1.y);
        uint4 u6 = *(const uint4*)(Tq + (size_t)(unsigned)c1.z);
        uint4 u7 = *(const uint4*)(Tq + (size_t)(unsigned)c1.w);
        ACC8(a0, u0) ACC8(a1, u1) ACC8(a0, u2) ACC8(a1, u3)
        ACC8(a0, u4) ACC8(a1, u5) ACC8(a0, u6) ACC8(a1, u7)
    }
    if (j < cnt) {
        int4 c0 = *(const int4*)(csr + base + j);
        uint4 u0 = *(const uint4*)(Tq + (size_t)(unsigned)c0.x);
        uint4 u1 = *(const uint4*)(Tq + (size_t)(unsigned)c0.y);
        uint4 u2 = *(const uint4*)(Tq + (size_t)(unsigned)c0.z);
        uint4 u3 = *(const uint4*)(Tq + (size_t)(unsigned)c0.w);
        ACC8(a0, u0) ACC8(a1, u1) ACC8(a0, u2) ACC8(a1, u3)
    }
    uint4 us = *(const uint4*)(Tq + (size_t)node * 128);   // self row
    ACC8(a1, us)
    float4 bb0 = ((const float4*)bias)[q * 2 + 0];
    float4 bb1 = ((const float4*)bias)[q * 2 + 1];
    float r[8];
    r[0] = fmaxf(dd * (a0[0] + a1[0]) + bb0.x, 0.f);
    r[1] = fmaxf(dd * (a0[1] + a1[1]) + bb0.y, 0.f);
    r[2] = fmaxf(dd * (a0[2] + a1[2]) + bb0.z, 0.f);
    r[3] = fmaxf(dd * (a0[3] + a1[3]) + bb0.w, 0.f);
    r[4] = fmaxf(dd * (a0[4] + a1[4]) + bb1.x, 0.f);
    r[5] = fmaxf(dd * (a0[5] + a1[5]) + bb1.y, 0.f);
    r[6] = fmaxf(dd * (a0[6] + a1[6]) + bb1.z, 0.f);
    r[7] = fmaxf(dd * (a0[7] + a1[7]) + bb1.w, 0.f);
    uint4 u;
    *(__half2*)&u.x = __floats2half2_rn(r[0], r[1]);
    *(__half2*)&u.y = __floats2half2_rn(r[2], r[3]);
    *(__half2*)&u.z = __floats2half2_rn(r[4], r[5]);
    *(__half2*)&u.w = __floats2half2_rn(r[6], r[7]);
    *(uint4*)&Rt[nl][q * 8] = u;
    __syncthreads();
    int w = tid >> 6, lane = tid & 63;
    int band = w >> 1, cg2 = w & 1;
    int ar = band * 16 + (lane & 15);
    int ak = (lane >> 4) * 8;
    half8 fa0 = *(const half8*)&Rt[ar][ak];
    half8 fa1 = *(const half8*)&Rt[ar][32 + ak];
    f32x4 acc0 = {0.f, 0.f, 0.f, 0.f}, acc1 = acc0;
    {
        int c0 = cg2 * 2, c1 = cg2 * 2 + 1;
        half8 b00 = *(const half8*)&Wt[c0 * 16 + (lane & 15)][ak];
        half8 b01 = *(const half8*)&Wt[c0 * 16 + (lane & 15)][32 + ak];
        half8 b10 = *(const half8*)&Wt[c1 * 16 + (lane & 15)][ak];
        half8 b11 = *(const half8*)&Wt[c1 * 16 + (lane & 15)][32 + ak];
        acc0 = __builtin_amdgcn_mfma_f32_16x16x32_f16(fa0, b00, acc0, 0, 0, 0);
        acc0 = __builtin_amdgcn_mfma_f32_16x16x32_f16(fa1, b01, acc0, 0, 0, 0);
        acc1 = __builtin_amdgcn_mfma_f32_16x16x32_f16(fa0, b10, acc1, 0, 0, 0);
        acc1 = __builtin_amdgcn_mfma_f32_16x16x32_f16(fa1, b11, acc1, 0, 0, 0);
    }
    __syncthreads();
#pragma unroll
    for (int i = 0; i < 4; ++i) {
        int rl = band * 16 + (lane >> 4) * 4 + i;
        float dsc = disT[rl];
        Rt[rl][(cg2 * 2 + 0) * 16 + (lane & 15)] = __float2half(acc0[i] * dsc);
        Rt[rl][(cg2 * 2 + 1) * 16 + (lane & 15)] = __float2half(acc1[i] * dsc);
    }
    __syncthreads();
    {
        int r8 = tid >> 3, c8 = tid & 7;
        int row = blockIdx.x * 32 + r8;
        *(uint4*)(TB + (size_t)row * 64 + c8 * 8) = *(const uint4*)&Rt[r8][c8 * 8];
    }
}

// ---- head gather: out[i] = dot(relu(dis*(sum TB rows)+b2), Wp) + bp ----
__global__ __launch_bounds__(256) void k_gatherg(
        const __half* __restrict__ T, const int* __restrict__ csr,
        const int* __restrict__ rowptr, const int* __restrict__ deg,
        const float* __restrict__ dis, const float* __restrict__ bias,
        const float* __restrict__ Wp, const float* __restrict__ bp,
        float* __restrict__ out, int n) {
    int tid = threadIdx.x;
    int q = tid & 7;
    int node = blockIdx.x * 32 + (tid >> 3);
    if (node >= n) return;
    int base = rowptr[node];
    int cnt  = deg[node];
    float dd = dis[node];
    const char* Tq = (const char*)T + q * 16;
    float a0[8], a1[8];
#pragma unroll
    for (int i = 0; i < 8; ++i) { a0[i] = 0.f; a1[i] = 0.f; }
    int j = 0;
    for (; j + 8 <= cnt; j += 8) {
        int4 c0 = *(const int4*)(csr + base + j);
        int4 c1 = *(const int4*)(csr + base + j + 4);
        uint4 u0 = *(const uint4*)(Tq + (size_t)(unsigned)c0.x);
        uint4 u1 = *(const uint4*)(Tq + (size_t)(unsigned)c0.y);
        uint4 u2 = *(const uint4*)(Tq + (size_t)(unsigned)c0.z);
        uint4 u3 = *(const uint4*)(Tq + (size_t)(unsigned)c0.w);
        uint4 u4 = *(const uint4*)(Tq + (size_t)(unsigned)c1.x);
        uint4 u5 = *(const uint4*)(Tq + (size_t)(unsigned)c1.y);
        uint4 u6 = *(const uint4*)(Tq + (size_t)(unsigned)c1.z);
        uint4 u7 = *(const uint4*)(Tq + (size_t)(unsigned)c1.w);
        ACC8(a0, u0) ACC8(a1, u1) ACC8(a0, u2) ACC8(a1, u3)
        ACC8(a0, u4) ACC8(a1, u5) ACC8(a0, u6) ACC8(a1, u7)
    }
    if (j < cnt) {
        int4 c0 = *(const int4*)(csr + base + j);
        uint4 u0 = *(const uint4*)(Tq + (size_t)(unsigned)c0.x);
        uint4 u1 = *(const uint4*)(Tq + (size_t)(unsigned)c0.y);
        uint4 u2 = *(const uint4*)(Tq + (size_t)(unsigned)c0.z);
        uint4 u3 = *(const uint4*)(Tq + (size_t)(unsigned)c0.w);
        ACC8(a0, u0) ACC8(a1, u1) ACC8(a0, u2) ACC8(a1, u3)
    }
    uint4 us = *(const uint4*)(Tq + (size_t)node * 128);
    ACC8(a1, us)
    float4 bb0 = ((const float4*)bias)[q * 2 + 0];
    float4 bb1 = ((const float4*)bias)[q * 2 + 1];
    float r[8];
    r[0] = fmaxf(dd * (a0[0] + a1[0]) + bb0.x, 0.f);
    r[1] = fmaxf(dd * (a0[1] + a1[1]) + bb0.y, 0.f);
    r[2] = fmaxf(dd * (a0[2] + a1[2]) + bb0.z, 0.f);
    r[3] = fmaxf(dd * (a0[3] + a1[3]) + bb0.w, 0.f);
    r[4] = fmaxf(dd * (a0[4] + a1[4]) + bb1.x, 0.f);
    r[5] = fmaxf(dd * (a0[5] + a1[5]) + bb1.y, 0.f);
    r[6] = fmaxf(dd * (a0[6] + a1[6]) + bb1.z, 0.f);
    r[7] = fmaxf(dd * (a0[7] + a1[7]) + bb1.w, 0.f);
    float4 w0 = ((const float4*)Wp)[q * 2 + 0];
    float4 w1 = ((const float4*)Wp)[q * 2 + 1];
    float s = r[0] * w0.x + r[1] * w0.y + r[2] * w0.z + r[3] * w0.w
            + r[4] * w1.x + r[5] * w1.y + r[6] * w1.z + r[7] * w1.w;
#pragma unroll
    for (int m = 1; m <= 4; m <<= 1) s += __shfl_xor(s, m);
    if (q == 0) out[node] = s + bp[0];
}

extern "C" void kernel_launch(void* const* d_in, const int* in_sizes, int n_in,
                              void* d_out, int out_size, void* d_ws, size_t ws_size,
                              hipStream_t stream) {
    const float* x  = (const float*)d_in[0];
    const int*   ei = (const int*)d_in[1];
    const float* W1 = (const float*)d_in[2];
    const float* b1 = (const float*)d_in[3];
    const float* W2 = (const float*)d_in[4];
    const float* b2 = (const float*)d_in[5];
    const float* Wp = (const float*)d_in[6];
    const float* bp = (const float*)d_in[7];
    float* out = (float*)d_out;

    const int N = GNN_N, E = GNN_E;
    const int* srcv = ei;
    const int* dstv = ei + E;

    // workspace layout (bytes):
    //   hist   @ 0          : HBLK*NBUCK ints = 782,000
    //   tot    @ 784,000    : 391 ints (own slot: bsort reads tot + writes dis)
    //   rowptr @ 787,200    : N ints
    //   deg    @ 1,187,200  : N ints
    //   dis    @ 1,587,200  : N floats
    //   csr    @ 1,987,200  : ~1.91M ints padded (7.61 MB)
    //   TA     @ 9,597,440  : (N+1)*64 fp16 (12.8 MB)
    //   TB     @ 22,400,000 : (N+1)*64 fp16 (12.8 MB)
    //   part   @ 35,200,256 : E u32 (6.4 MB)    [total ~41.6 MB]
    char* ws = (char*)d_ws;
    int*    hist   = (int*)(ws + 0);
    int*    tot    = (int*)(ws + 784000);
    int*    rowptr = (int*)(ws + 787200);
    int*    deg    = (int*)(ws + 1187200);
    float*  dis    = (float*)(ws + 1587200);
    int*    csr    = (int*)(ws + 1987200);
    __half* TA     = (__half*)(ws + 9597440);
    __half* TB     = (__half*)(ws + 22400000);
    unsigned int* part = (unsigned int*)(ws + 35200256);

    // CSR build (4 kernels; bucket bases computed in-block from tot)
    k_hist <<<HBLK, 256, 0, stream>>>(dstv, hist, TA, TB);
    k_cscan<<<(NBUCK + SCTILE - 1) / SCTILE, 256, 0, stream>>>(hist, tot);
    k_part <<<NBLK, 256, 0, stream>>>(srcv, dstv, hist, tot, part);
    k_bsort<<<NBUCK, 256, 0, stream>>>(part, tot, csr, rowptr, deg, dis);

    // layer 1 matmul: TA = fp16((x@W1)*dis)
    k_mmf<<<(N + 63) / 64, 256, 0, stream>>>(x, W1, dis, TA, N);
    // fused layer-1 gather + layer-2 matmul: TB = fp16((relu(gather)@W2)*dis)
    k_gatherW2<<<N / 32, 256, 0, stream>>>(TA, csr, rowptr, deg, dis, b1, W2, TB);
    // layer-2 gather + head
    k_gatherg<<<(N + 31) / 32, 256, 0, stream>>>(TB, csr, rowptr, deg, dis,
                                                 b2, Wp, bp, out, N);
}